// Round 6
// baseline (164.028 us; speedup 1.0000x reference)
//
#include <hip/hip_runtime.h>

#define D 128
#define BSHIFT 5                 // 32 rows per bucket
#define BCAP 1024                // entries/bucket; mean 512, +16 sigma + pad room
#define EPB_A 2048               // edges per pass-A block

typedef unsigned short ushort_t;
typedef unsigned int uint_t;
typedef __attribute__((ext_vector_type(8))) short short8_t;   // 8 bf16 = 4 VGPR
typedef __attribute__((ext_vector_type(4))) float f32x4_t;    // mfma C/D
typedef const __attribute__((address_space(1))) void* gas_cptr;
typedef __attribute__((address_space(3))) void* las_ptr;

// ---- edge-index dtype probe (int64 vs int32), wave-uniform, ~free ----
__device__ __forceinline__ bool eidx_is64(const int* eidx) {
    int lane = threadIdx.x & 63;
    int probe = eidx[2 * lane + 1];              // L2-hit after first wave
    return __ballot(probe != 0) == 0ULL;         // int64 high halves all zero
}

__device__ __forceinline__ uint_t f2bf(float f) {
    union { float f; uint_t i; } v; v.f = f;
    return (v.i + 0x7fffu + ((v.i >> 16) & 1u)) >> 16;   // RNE
}
__device__ __forceinline__ float bf_lo(uint_t w) {
    union { uint_t i; float f; } v; v.i = w << 16; return v.f;
}
__device__ __forceinline__ float bf_hi(uint_t w) {
    union { uint_t i; float f; } v; v.i = w & 0xffff0000u; return v.f;
}

// ==== Kernel 1: bucketA + fp32->bf16 conv of x AND W (all independent) ====
// blocks [0, ab):             coarse-bucket edges (reg-cached single read)
// blocks [ab, ab+cvb):        x fp32 -> bf16 (block ab also zeroes dummy row)
// blocks [ab+cvb, ab+cvb+8):  W fp32 -> bf16
__global__ __launch_bounds__(256) void pre_kernel(
    const int* __restrict__ eidx, int* __restrict__ gcur,
    int* __restrict__ bucket, int E, int NBUK, int ab,
    const float* __restrict__ x, uint_t* __restrict__ xb, int total8, int cvb,
    const float* __restrict__ Wsrc, uint_t* __restrict__ wb, int N) {
    int t = threadIdx.x;

    if ((int)blockIdx.x >= ab) {                 // ---- conv roles ----
        if (xb == nullptr) return;
        int cb = blockIdx.x - ab;
        if (cb < cvb) {                          // x conversion
            int i = cb * 256 + t;
            if (i < total8) {                    // one thread = 8 elems
                const float4* p = (const float4*)(x + (size_t)i * 8);
                float4 a = p[0], b = p[1];
                uint4 o;
                o.x = f2bf(a.x) | (f2bf(a.y) << 16);
                o.y = f2bf(a.z) | (f2bf(a.w) << 16);
                o.z = f2bf(b.x) | (f2bf(b.y) << 16);
                o.w = f2bf(b.z) | (f2bf(b.w) << 16);
                *(uint4*)(xb + (size_t)i * 4) = o;
            }
            if (cb == 0 && t < 16) {
                // dummy zero row at index N (16 * uint4 = 256 B)
                uint4 z; z.x = 0u; z.y = 0u; z.z = 0u; z.w = 0u;
                ((uint4*)(xb + (size_t)N * (D / 2)))[t] = z;
            }
        } else {                                 // W conversion (D*D/8 = 2048 items)
            int i = (cb - cvb) * 256 + t;
            if (i < D * D / 8) {
                const float4* p = (const float4*)(Wsrc + (size_t)i * 8);
                float4 a = p[0], b = p[1];
                uint4 o;
                o.x = f2bf(a.x) | (f2bf(a.y) << 16);
                o.y = f2bf(a.z) | (f2bf(a.w) << 16);
                o.z = f2bf(b.x) | (f2bf(b.y) << 16);
                o.w = f2bf(b.z) | (f2bf(b.w) << 16);
                *(uint4*)(wb + (size_t)i * 4) = o;
            }
        }
        return;
    }

    // ---- bucketA role: coarse-bucket edges, single edge read ----
    __shared__ int lhist[2048];   // supports N <= 65536 at 32 rows/bucket
    __shared__ int lbase[2048];
    bool is64 = eidx_is64(eidx);
    for (int i = t; i < NBUK; i += 256) lhist[i] = 0;
    __syncthreads();

    int e0 = blockIdx.x * EPB_A;
    int e1 = min(e0 + EPB_A, E);
    int rr[8], cc[8];
    #pragma unroll
    for (int k = 0; k < 8; ++k) {             // read each edge ONCE into regs
        int e = e0 + t + k * 256;
        rr[k] = -1;
        if (e < e1) {
            if (is64) { rr[k] = eidx[2 * e]; cc[k] = eidx[2 * E + 2 * e]; }
            else      { rr[k] = eidx[e];     cc[k] = eidx[E + e]; }
            atomicAdd(&lhist[rr[k] >> BSHIFT], 1);
        }
    }
    __syncthreads();
    for (int i = t; i < NBUK; i += 256) {
        int h = lhist[i];
        lbase[i] = (h > 0) ? atomicAdd(&gcur[i], h) : 0;
        lhist[i] = 0;
    }
    __syncthreads();
    #pragma unroll
    for (int k = 0; k < 8; ++k) {             // scatter from regs (no re-read)
        if (rr[k] >= 0) {
            int b = rr[k] >> BSHIFT;
            int p = atomicAdd(&lhist[b], 1);   // LDS: cheap
            int idx = lbase[b] + p;
            if (idx < BCAP) bucket[b * BCAP + idx] = ((rr[k] & 31) << 24) | cc[k];
        }
    }
}

// ==== Kernel 2: FUSED bucketB (LDS) + global_load_lds gather + MFMA ====
// One 256-thread block per 32-row bucket.
//  step 1: packed 8-padded per-row edge list built in LDS (pad = dummy row N).
//  step 2: gather via __builtin_amdgcn_global_load_lds — staging data costs
//          ZERO VGPRs, so pipeline depth lives in the vmcnt queue instead of
//          the register file (R2-R5 all compiled to ~6 loads in flight at
//          VGPR<=56 no matter the source-level depth). Per wave: private
//          2 x 4 KB double buffer; each batch = 4 instructions staging 4
//          edges/quarter (lane l -> uniform base + l*16: quarter q's row
//          lands at q*256+sl*16). Issue batch k+1, s_waitcnt vmcnt(4),
//          consume batch k. Wave-uniform trip count (shfl-max); finished
//          quarters stage the L1-resident zero row and add exact zeros.
//  step 3: [32x128]x[128x128] on the matrix pipe, B straight from bf16 W.
#define ISSUE(c, bufsel)                                                      \
    {                                                                         \
        ushort_t* db_ = wstage + (bufsel) * 2048;                             \
        __builtin_amdgcn_global_load_lds(                                     \
            (gas_cptr)(xb + (size_t)(c).x * D + 8 * sl),                      \
            (las_ptr)(db_), 16, 0, 0);                                        \
        __builtin_amdgcn_global_load_lds(                                     \
            (gas_cptr)(xb + (size_t)(c).y * D + 8 * sl),                      \
            (las_ptr)(db_ + 512), 16, 0, 0);                                  \
        __builtin_amdgcn_global_load_lds(                                     \
            (gas_cptr)(xb + (size_t)(c).z * D + 8 * sl),                      \
            (las_ptr)(db_ + 1024), 16, 0, 0);                                 \
        __builtin_amdgcn_global_load_lds(                                     \
            (gas_cptr)(xb + (size_t)(c).w * D + 8 * sl),                      \
            (las_ptr)(db_ + 1536), 16, 0, 0);                                 \
    }

#define ACC(v)                                                                \
    a0 += bf_lo((v).x); a1 += bf_hi((v).x);                                   \
    a2 += bf_lo((v).y); a3 += bf_hi((v).y);                                   \
    a4 += bf_lo((v).z); a5 += bf_hi((v).z);                                   \
    a6 += bf_lo((v).w); a7 += bf_hi((v).w);

__global__ __launch_bounds__(256, 3) void fused_bf_kernel(
    const ushort_t* __restrict__ xb, const int* __restrict__ gcur,
    const int* __restrict__ bucket, const ushort_t* __restrict__ Wb,
    const float* __restrict__ bias, float* __restrict__ out, int N) {
    __shared__ int sE[1024];            // 4 KiB   packed 8-padded edge list
    __shared__ int lcnt[32], lpos[32], lstart[32];
    __shared__ ushort_t sA[32 * 136];   // 8.5 KiB [n][k] bf16, +8-short row pad
    __shared__ ushort_t stage[16384];   // 32 KiB  4 waves x 2 bufs x 4 KB
    int t = threadIdx.x;
    int b = blockIdx.x;

    // ---- step 1: bucketB in LDS ----
    if (t < 32) { lcnt[t] = 0; lpos[t] = 0; }
    __syncthreads();
    int tot = min(gcur[b], BCAP);
    const int* bp = bucket + (size_t)b * BCAP;
    for (int i = t; i < tot; i += 256)
        atomicAdd(&lcnt[bp[i] >> 24], 1);
    __syncthreads();
    if (t == 0) {
        int run = 0;
        #pragma unroll
        for (int i = 0; i < 32; ++i) {
            lstart[i] = run;
            run += (lcnt[i] + 7) & ~7;     // 8-aligned, 8-padded segments
        }                                  // run <= raw + 32*7 <= 1024 whp
    }
    __syncthreads();
    for (int i = t; i < tot; i += 256) {
        int v = bp[i];
        int rl = v >> 24;
        int p = atomicAdd(&lpos[rl], 1);
        int idx = lstart[rl] + p;
        if (idx < 1024) sE[idx] = v & 0xFFFFFF;
    }
    if (t < 32) {                          // pad with dummy (zero) row index N
        int c0 = lcnt[t];
        int pe = (c0 + 7) & ~7;
        for (int p = c0; p < pe; ++p) {
            int idx = lstart[t] + p;
            if (idx < 1024) sE[idx] = N;
        }
    }
    __syncthreads();

    // ---- step 2: gather means -> bf16 LDS A-tile (global_load_lds pipe) ----
    int lane = t & 63, wave = t >> 6;
    int qi = t >> 4, sl = t & 15;          // quarter [0,16), sublane [0,16)
    int nbase = b << BSHIFT;               // 32 rows per block
    ushort_t* wstage = stage + (wave << 12);   // 8 KB (4096 ushorts) per wave

    #pragma unroll
    for (int quad = 0; quad < 2; ++quad) {
        int n = 2 * qi + quad;             // row within bucket [0,32)
        int nr = lcnt[n];
        int st = lstart[n];                // 8-aligned
        int trips = ((nr + 7) & ~7) >> 2;  // batches of 4 edges (even count)
        int wmax = trips;                  // wave-uniform trip count
        wmax = max(wmax, __shfl_xor(wmax, 16));
        wmax = max(wmax, __shfl_xor(wmax, 32));
        float a0 = 0.f, a1 = 0.f, a2 = 0.f, a3 = 0.f;
        float a4 = 0.f, a5 = 0.f, a6 = 0.f, a7 = 0.f;
        if (wmax > 0) {
            int4 c0 = (0 < trips) ? *(const int4*)(sE + st)
                                  : make_int4(N, N, N, N);
            ISSUE(c0, 0)
            for (int bt = 0; bt < wmax; ++bt) {
                int buf = bt & 1;
                if (bt + 1 < wmax) {       // wave-uniform branch
                    int4 cn = (bt + 1 < trips)
                        ? *(const int4*)(sE + st + 4 * (bt + 1))
                        : make_int4(N, N, N, N);
                    ISSUE(cn, buf ^ 1)
                    asm volatile("s_waitcnt vmcnt(4)" ::: "memory");
                } else {
                    asm volatile("s_waitcnt vmcnt(0)" ::: "memory");
                }
                __builtin_amdgcn_sched_barrier(0);
                const ushort_t* sb = wstage + buf * 2048;
                uint4 v0 = *(const uint4*)(sb +    0 + lane * 8);
                uint4 v1 = *(const uint4*)(sb +  512 + lane * 8);
                uint4 v2 = *(const uint4*)(sb + 1024 + lane * 8);
                uint4 v3 = *(const uint4*)(sb + 1536 + lane * 8);
                ACC(v0) ACC(v1) ACC(v2) ACC(v3)
            }
        }
        float inv = (nr > 0) ? 1.0f / (float)nr : 0.0f;
        uint4 pk;
        pk.x = f2bf(a0 * inv) | (f2bf(a1 * inv) << 16);
        pk.y = f2bf(a2 * inv) | (f2bf(a3 * inv) << 16);
        pk.z = f2bf(a4 * inv) | (f2bf(a5 * inv) << 16);
        pk.w = f2bf(a6 * inv) | (f2bf(a7 * inv) << 16);
        *(uint4*)(sA + n * 136 + 8 * sl) = pk;
    }
    __syncthreads();

    // ---- step 3: out[n][j] = mean[n][:] . W[j][:] + b[j]  via MFMA ----
    // 4 waves: rt = wave&1 (2 row-tiles of 16), jgrp = wave>>1 (4 j-tiles).
    // A-frag: lane holds A[l&15][(l>>4)*8 + e];  B = W^T so lane reads
    // W[j = jt*16 + (l&15)][k .. k+7] -- contiguous global bf16.
    {
        int rt = wave & 1, jgrp = wave >> 1;
        int ml = lane & 15, kh = lane >> 4;
        short8_t afr[4];
        #pragma unroll
        for (int ks = 0; ks < 4; ++ks)
            afr[ks] = *(const short8_t*)(sA + (rt * 16 + ml) * 136 + ks * 32 + kh * 8);
        f32x4_t acc[4];
        #pragma unroll
        for (int q = 0; q < 4; ++q) acc[q] = (f32x4_t){0.f, 0.f, 0.f, 0.f};
        #pragma unroll
        for (int q = 0; q < 4; ++q) {
            int j = (jgrp * 4 + q) * 16 + ml;
            #pragma unroll
            for (int ks = 0; ks < 4; ++ks) {
                short8_t bfr = *(const short8_t*)(Wb + (size_t)j * D + ks * 32 + kh * 8);
                acc[q] = __builtin_amdgcn_mfma_f32_16x16x32_bf16(afr[ks], bfr, acc[q], 0, 0, 0);
            }
        }
        // C/D layout: col = lane&15 (j), row = (lane>>4)*4 + reg (n)
        #pragma unroll
        for (int q = 0; q < 4; ++q) {
            int j = (jgrp * 4 + q) * 16 + ml;
            float bj = bias[j];
            #pragma unroll
            for (int r = 0; r < 4; ++r) {
                int gn = nbase + rt * 16 + kh * 4 + r;
                if (gn < N) out[(size_t)gn * D + j] = acc[q][r] + bj;
            }
        }
    }
}

// ---- fallback Pass B: bucket -> packed global elist (fp32 path only) ----
__global__ __launch_bounds__(256) void prep_kernel(
    const int* __restrict__ gcur, const int* __restrict__ bucket,
    int* __restrict__ elist, int* __restrict__ cnt,
    int* __restrict__ start, int N, int NBUK) {
    __shared__ int lcnt[32], lpos[32], lstart[32];
    int t = threadIdx.x;
    int b = blockIdx.x;
    if (t < 32) { lcnt[t] = 0; lpos[t] = 0; }
    __syncthreads();
    int tot = min(gcur[b], BCAP);
    const int* bp = bucket + (size_t)b * BCAP;
    for (int i = t; i < tot; i += 256)
        atomicAdd(&lcnt[bp[i] >> 24], 1);
    __syncthreads();
    if (t == 0) {
        int run = 0;
        #pragma unroll
        for (int i = 0; i < 32; ++i) {
            lstart[i] = run;
            run += (lcnt[i] + 3) & ~3;     // 4-aligned segments
        }
    }
    __syncthreads();
    for (int i = t; i < tot; i += 256) {
        int v = bp[i];
        int rl = v >> 24;
        int p = atomicAdd(&lpos[rl], 1);
        int idx = lstart[rl] + p;
        if (idx < BCAP) elist[(size_t)b * BCAP + idx] = v & 0xFFFFFF;
    }
    if (t < 32) {
        int gr = (b << BSHIFT) + t;
        if (gr < N) { cnt[gr] = lcnt[t]; start[gr] = b * BCAP + lstart[t]; }
    }
}

// ---- fp32 fused variant (proven; used when ws can't hold xb).
// Reads only i < cnt entries. ----
__global__ __launch_bounds__(256, 6) void fused_kernel(
    const float* __restrict__ x, const int* __restrict__ elist,
    const int* __restrict__ cnt, const int* __restrict__ start,
    const float* __restrict__ W, const float* __restrict__ bias,
    float* __restrict__ out, int N) {
    __shared__ float sT[128 * 36];
    __shared__ float wc[16 * 132];
    int t = threadIdx.x;
    int lane = t & 63, wave = t >> 6;
    int half = lane >> 5, sl = lane & 31;
    int nbase = blockIdx.x * 32;

    #pragma unroll
    for (int pair = 0; pair < 4; ++pair) {
        int n = wave * 8 + pair * 2 + half;
        int gn = nbase + n;
        int nr  = (gn < N) ? cnt[gn]   : 0;
        int beg = (gn < N) ? start[gn] : 0;
        int nro  = __shfl(nr, lane ^ 32);
        int both = min(nr, nro);
        float ax = 0.f, ay = 0.f, az = 0.f, aw = 0.f;
        int i = 0;
        for (; i + 8 <= both; i += 8) {
            int4 cA = *(const int4*)(elist + beg + i);
            int4 cB = *(const int4*)(elist + beg + i + 4);
            float4 v0 = *(const float4*)(x + (size_t)cA.x * D + 4 * sl);
            float4 v1 = *(const float4*)(x + (size_t)cA.y * D + 4 * sl);
            float4 v2 = *(const float4*)(x + (size_t)cA.z * D + 4 * sl);
            float4 v3 = *(const float4*)(x + (size_t)cA.w * D + 4 * sl);
            float4 v4 = *(const float4*)(x + (size_t)cB.x * D + 4 * sl);
            float4 v5 = *(const float4*)(x + (size_t)cB.y * D + 4 * sl);
            float4 v6 = *(const float4*)(x + (size_t)cB.z * D + 4 * sl);
            float4 v7 = *(const float4*)(x + (size_t)cB.w * D + 4 * sl);
            ax += ((v0.x + v1.x) + (v2.x + v3.x)) + ((v4.x + v5.x) + (v6.x + v7.x));
            ay += ((v0.y + v1.y) + (v2.y + v3.y)) + ((v4.y + v5.y) + (v6.y + v7.y));
            az += ((v0.z + v1.z) + (v2.z + v3.z)) + ((v4.z + v5.z) + (v6.z + v7.z));
            aw += ((v0.w + v1.w) + (v2.w + v3.w)) + ((v4.w + v5.w) + (v6.w + v7.w));
        }
        for (; i < nr; ++i) {
            int c0 = elist[beg + i];
            float4 v = *(const float4*)(x + (size_t)c0 * D + 4 * sl);
            ax += v.x; ay += v.y; az += v.z; aw += v.w;
        }
        float inv = (nr > 0) ? 1.0f / (float)nr : 0.0f;
        int k0 = 4 * sl;
        sT[(k0 + 0) * 36 + n] = ax * inv;
        sT[(k0 + 1) * 36 + n] = ay * inv;
        sT[(k0 + 2) * 36 + n] = az * inv;
        sT[(k0 + 3) * 36 + n] = aw * inv;
    }

    int jg = t & 31, ng = t >> 5;
    int j0 = jg * 4, n0 = ng * 4;
    float acc[4][4] = {};
    for (int kc = 0; kc < 8; ++kc) {
        __syncthreads();
        #pragma unroll
        for (int i = 0; i < 8; ++i) {
            int idx = t + i * 256;
            int j = idx >> 4, kk = idx & 15;
            wc[kk * 132 + j] = W[j * D + kc * 16 + kk];
        }
        __syncthreads();
        #pragma unroll
        for (int kk = 0; kk < 16; ++kk) {
            int k = kc * 16 + kk;
            float4 s4 = *(const float4*)(sT + k * 36 + n0);
            float4 w4 = *(const float4*)(wc + kk * 132 + j0);
            acc[0][0] = fmaf(s4.x, w4.x, acc[0][0]); acc[0][1] = fmaf(s4.x, w4.y, acc[0][1]);
            acc[0][2] = fmaf(s4.x, w4.z, acc[0][2]); acc[0][3] = fmaf(s4.x, w4.w, acc[0][3]);
            acc[1][0] = fmaf(s4.y, w4.x, acc[1][0]); acc[1][1] = fmaf(s4.y, w4.y, acc[1][1]);
            acc[1][2] = fmaf(s4.y, w4.z, acc[1][2]); acc[1][3] = fmaf(s4.y, w4.w, acc[1][3]);
            acc[2][0] = fmaf(s4.z, w4.x, acc[2][0]); acc[2][1] = fmaf(s4.z, w4.y, acc[2][1]);
            acc[2][2] = fmaf(s4.z, w4.z, acc[2][2]); acc[2][3] = fmaf(s4.z, w4.w, acc[2][3]);
            acc[3][0] = fmaf(s4.w, w4.x, acc[3][0]); acc[3][1] = fmaf(s4.w, w4.y, acc[3][1]);
            acc[3][2] = fmaf(s4.w, w4.z, acc[3][2]); acc[3][3] = fmaf(s4.w, w4.w, acc[3][3]);
        }
    }
    float4 b4 = *(const float4*)(bias + j0);
    #pragma unroll
    for (int i = 0; i < 4; ++i) {
        int gn = nbase + n0 + i;
        if (gn >= N) continue;
        float4 o;
        o.x = acc[i][0] + b4.x;
        o.y = acc[i][1] + b4.y;
        o.z = acc[i][2] + b4.z;
        o.w = acc[i][3] + b4.w;
        *(float4*)(out + (size_t)gn * D + j0) = o;
    }
}

// ==== last-resort fallback: atomic scatter + divide + gemm (proven) ====
__global__ __launch_bounds__(256) void scatter_kernel(
    const float* __restrict__ x, const int* __restrict__ eidx,
    float* summed, float* __restrict__ counts, int E) {
    int t = blockIdx.x * 256 + threadIdx.x;
    int lane = threadIdx.x & 63;
    bool is64 = eidx_is64(eidx);
    int e = t >> 6;
    if (e >= E) return;
    int d = lane * 2;
    int r, c;
    if (is64) { r = eidx[2 * e]; c = eidx[2 * E + 2 * e]; }
    else      { r = eidx[e];     c = eidx[E + e]; }
    float2 v = *(const float2*)(x + (size_t)c * D + d);
    float* dst = summed + (size_t)r * D + d;
    atomicAdd(dst, v.x);
    atomicAdd(dst + 1, v.y);
    if (lane == 0) atomicAdd(counts + r, 1.0f);
}

__global__ __launch_bounds__(256) void divide_kernel(
    float* __restrict__ sums, const float* __restrict__ counts, int N) {
    int g = blockIdx.x * 256 + threadIdx.x;
    int r = g >> 6, lane = g & 63;
    if (r >= N) return;
    float inv = 1.0f / fmaxf(counts[r], 1.0f);
    float2* p = (float2*)(sums + (size_t)r * D + 2 * lane);
    float2 v = *p;
    v.x *= inv; v.y *= inv;
    *p = v;
}

__global__ __launch_bounds__(256) void gemm_kernel(
    float* inout, const float* __restrict__ W,
    const float* __restrict__ bias, int N) {
    __shared__ float sT[128 * 36];
    __shared__ float wc[32 * 132];
    int t = threadIdx.x;
    int nbase = blockIdx.x * 32;
    #pragma unroll
    for (int i = 0; i < 16; ++i) {
        int idx = t + i * 256;
        int n = idx >> 7, k = idx & 127;
        int gn = nbase + n;
        sT[k * 36 + n] = (gn < N) ? inout[(size_t)gn * D + k] : 0.0f;
    }
    int jg = t & 31, ng = t >> 5;
    int j0 = jg * 4, n0 = ng * 4;
    float acc[4][4] = {};
    for (int kc = 0; kc < 4; ++kc) {
        __syncthreads();
        #pragma unroll
        for (int i = 0; i < 16; ++i) {
            int idx = t + i * 256;
            int j = idx >> 5, kk = idx & 31;
            wc[kk * 132 + j] = W[j * D + kc * 32 + kk];
        }
        __syncthreads();
        #pragma unroll 8
        for (int kk = 0; kk < 32; ++kk) {
            int k = kc * 32 + kk;
            float4 s4 = *(const float4*)(sT + k * 36 + n0);
            float4 w4 = *(const float4*)(wc + kk * 132 + j0);
            acc[0][0] = fmaf(s4.x, w4.x, acc[0][0]); acc[0][1] = fmaf(s4.x, w4.y, acc[0][1]);
            acc[0][2] = fmaf(s4.x, w4.z, acc[0][2]); acc[0][3] = fmaf(s4.x, w4.w, acc[0][3]);
            acc[1][0] = fmaf(s4.y, w4.x, acc[1][0]); acc[1][1] = fmaf(s4.y, w4.y, acc[1][1]);
            acc[1][2] = fmaf(s4.y, w4.z, acc[1][2]); acc[1][3] = fmaf(s4.y, w4.w, acc[1][3]);
            acc[2][0] = fmaf(s4.z, w4.x, acc[2][0]); acc[2][1] = fmaf(s4.z, w4.y, acc[2][1]);
            acc[2][2] = fmaf(s4.z, w4.z, acc[2][2]); acc[2][3] = fmaf(s4.z, w4.w, acc[2][3]);
            acc[3][0] = fmaf(s4.w, w4.x, acc[3][0]); acc[3][1] = fmaf(s4.w, w4.y, acc[3][1]);
            acc[3][2] = fmaf(s4.w, w4.z, acc[3][2]); acc[3][3] = fmaf(s4.w, w4.w, acc[3][3]);
        }
    }
    float4 b4 = *(const float4*)(bias + j0);
    #pragma unroll
    for (int i = 0; i < 4; ++i) {
        int gn = nbase + n0 + i;
        if (gn >= N) continue;
        float4 o;
        o.x = acc[i][0] + b4.x;
        o.y = acc[i][1] + b4.y;
        o.z = acc[i][2] + b4.z;
        o.w = acc[i][3] + b4.w;
        *(float4*)(inout + (size_t)gn * D + j0) = o;
    }
}

extern "C" void kernel_launch(void* const* d_in, const int* in_sizes, int n_in,
                              void* d_out, int out_size, void* d_ws, size_t ws_size,
                              hipStream_t stream) {
    // setup_inputs order: x, edge_index, batch_size, num_nodes, W, b
    const float* x = (const float*)d_in[0];
    const int* eidx = (const int*)d_in[1];
    const float* W = (const float*)d_in[4];
    const float* b = (const float*)d_in[5];
    float* out = (float*)d_out;

    int N = in_sizes[0] / D;   // 50000
    int E = in_sizes[1] / 2;   // 800000
    int NBUK = (N + 31) >> BSHIFT;   // 1563
    int ab = (E + EPB_A - 1) / EPB_A;

    // ws layout, 256B-aligned segments (cnt/start/elist used by fallback only).
    size_t o0 = 0;
    size_t o_gc = o0;  o0 += ((size_t)NBUK * 4 + 255) & ~255ULL;
    size_t o_cn = o0;  o0 += ((size_t)N * 4 + 255) & ~255ULL;
    size_t o_st = o0;  o0 += ((size_t)N * 4 + 255) & ~255ULL;
    size_t o_bk = o0;  o0 += (size_t)NBUK * BCAP * 4;
    size_t o_el = o0;  o0 += (size_t)NBUK * BCAP * 4;
    size_t base_need = o0;
    size_t o_xb = o0;  o0 += (((size_t)(N + 1) * D * 2) + 255) & ~255ULL;  // bf16 x + dummy
    size_t o_wb = o0;  size_t bf_need = o0 + (size_t)D * D * 2;            // bf16 W

    bool cap_ok = (N <= 65536) && ((size_t)NBUK * BCAP >= (size_t)E);

    int cvb = (N * D / 8 + 255) / 256;
    int wvb = (D * D / 8 + 255) / 256;   // 8 blocks for W conversion

    if (cap_ok && ws_size >= bf_need) {
        char* ws = (char*)d_ws;
        int*      gcur  = (int*)(ws + o_gc);
        int*      bkt   = (int*)(ws + o_bk);
        ushort_t* xb    = (ushort_t*)(ws + o_xb);
        ushort_t* wb    = (ushort_t*)(ws + o_wb);

        hipMemsetAsync(gcur, 0, (size_t)NBUK * 4, stream);  // 6 KB only
        pre_kernel<<<ab + cvb + wvb, 256, 0, stream>>>(
            eidx, gcur, bkt, E, NBUK, ab,
            x, (uint_t*)xb, N * D / 8, cvb, W, (uint_t*)wb, N);
        fused_bf_kernel<<<NBUK, 256, 0, stream>>>(xb, gcur, bkt, wb, b, out, N);
    } else if (cap_ok && ws_size >= base_need) {
        char* ws = (char*)d_ws;
        int* gcur  = (int*)(ws + o_gc);
        int* cnt   = (int*)(ws + o_cn);
        int* start = (int*)(ws + o_st);
        int* bkt   = (int*)(ws + o_bk);
        int* elist = (int*)(ws + o_el);
        int fb = (N + 31) / 32;

        hipMemsetAsync(gcur, 0, (size_t)NBUK * 4, stream);
        pre_kernel<<<ab, 256, 0, stream>>>(
            eidx, gcur, bkt, E, NBUK, ab,
            nullptr, nullptr, 0, 0, nullptr, nullptr, N);
        prep_kernel<<<NBUK, 256, 0, stream>>>(gcur, bkt, elist, cnt, start, N, NBUK);
        fused_kernel<<<fb, 256, 0, stream>>>(x, elist, cnt, start, W, b, out, N);
    } else {
        float* counts = (float*)d_ws;
        int fb = (N + 31) / 32;
        hipMemsetAsync(d_out, 0, (size_t)N * D * sizeof(float), stream);
        hipMemsetAsync(d_ws, 0, (size_t)N * sizeof(float), stream);
        int sb = (E * 64 + 255) / 256;
        scatter_kernel<<<sb, 256, 0, stream>>>(x, eidx, out, counts, E);
        int db = (N * 64 + 255) / 256;
        divide_kernel<<<db, 256, 0, stream>>>(out, counts, N);
        gemm_kernel<<<fb, 256, 0, stream>>>(out, W, b, N);
    }
}

// Round 7
// 157.777 us; speedup vs baseline: 1.0396x; 1.0396x over previous
//
#include <hip/hip_runtime.h>

#define D 128
#define BSHIFT 5                 // 32 rows per bucket
#define BCAP 1024                // entries/bucket; mean 512, +16 sigma
#define EPB_A 2048               // edges per pass-A block

typedef unsigned short ushort_t;
typedef unsigned int uint_t;
typedef __attribute__((ext_vector_type(8))) short short8_t;   // 8 bf16 = 4 VGPR
typedef __attribute__((ext_vector_type(4))) float f32x4_t;    // mfma C/D
typedef __attribute__((ext_vector_type(4))) uint_t uint4_t;   // asm ds_read dst
typedef const __attribute__((address_space(1))) void* gas_cptr;
typedef __attribute__((address_space(3))) void* las_ptr;
typedef const __attribute__((address_space(3))) ushort_t* las_cushort;

// ---- edge-index dtype probe (int64 vs int32), wave-uniform, ~free ----
__device__ __forceinline__ bool eidx_is64(const int* eidx) {
    int lane = threadIdx.x & 63;
    int probe = eidx[2 * lane + 1];              // L2-hit after first wave
    return __ballot(probe != 0) == 0ULL;         // int64 high halves all zero
}

__device__ __forceinline__ uint_t f2bf(float f) {
    union { float f; uint_t i; } v; v.f = f;
    return (v.i + 0x7fffu + ((v.i >> 16) & 1u)) >> 16;   // RNE
}
__device__ __forceinline__ float bf_lo(uint_t w) {
    union { uint_t i; float f; } v; v.i = w << 16; return v.f;
}
__device__ __forceinline__ float bf_hi(uint_t w) {
    union { uint_t i; float f; } v; v.i = w & 0xffff0000u; return v.f;
}

// ==== Kernel 1: bucketA + fp32->bf16 conv of x AND W (all independent) ====
__global__ __launch_bounds__(256) void pre_kernel(
    const int* __restrict__ eidx, int* __restrict__ gcur,
    int* __restrict__ bucket, int E, int NBUK, int ab,
    const float* __restrict__ x, uint_t* __restrict__ xb, int total8, int cvb,
    const float* __restrict__ Wsrc, uint_t* __restrict__ wb, int N) {
    int t = threadIdx.x;

    if ((int)blockIdx.x >= ab) {                 // ---- conv roles ----
        if (xb == nullptr) return;
        int cb = blockIdx.x - ab;
        if (cb < cvb) {                          // x conversion
            int i = cb * 256 + t;
            if (i < total8) {                    // one thread = 8 elems
                const float4* p = (const float4*)(x + (size_t)i * 8);
                float4 a = p[0], b = p[1];
                uint4 o;
                o.x = f2bf(a.x) | (f2bf(a.y) << 16);
                o.y = f2bf(a.z) | (f2bf(a.w) << 16);
                o.z = f2bf(b.x) | (f2bf(b.y) << 16);
                o.w = f2bf(b.z) | (f2bf(b.w) << 16);
                *(uint4*)(xb + (size_t)i * 4) = o;
            }
            if (cb == 0 && t < 16) {
                // dummy zero row at index N (16 * uint4 = 256 B)
                uint4 z; z.x = 0u; z.y = 0u; z.z = 0u; z.w = 0u;
                ((uint4*)(xb + (size_t)N * (D / 2)))[t] = z;
            }
        } else {                                 // W conversion (D*D/8 = 2048 items)
            int i = (cb - cvb) * 256 + t;
            if (i < D * D / 8) {
                const float4* p = (const float4*)(Wsrc + (size_t)i * 8);
                float4 a = p[0], b = p[1];
                uint4 o;
                o.x = f2bf(a.x) | (f2bf(a.y) << 16);
                o.y = f2bf(a.z) | (f2bf(a.w) << 16);
                o.z = f2bf(b.x) | (f2bf(b.y) << 16);
                o.w = f2bf(b.z) | (f2bf(b.w) << 16);
                *(uint4*)(wb + (size_t)i * 4) = o;
            }
        }
        return;
    }

    // ---- bucketA role: coarse-bucket edges, single edge read ----
    __shared__ int lhist[2048];   // supports N <= 65536 at 32 rows/bucket
    __shared__ int lbase[2048];
    bool is64 = eidx_is64(eidx);
    for (int i = t; i < NBUK; i += 256) lhist[i] = 0;
    __syncthreads();

    int e0 = blockIdx.x * EPB_A;
    int e1 = min(e0 + EPB_A, E);
    int rr[8], cc[8];
    #pragma unroll
    for (int k = 0; k < 8; ++k) {             // read each edge ONCE into regs
        int e = e0 + t + k * 256;
        rr[k] = -1;
        if (e < e1) {
            if (is64) { rr[k] = eidx[2 * e]; cc[k] = eidx[2 * E + 2 * e]; }
            else      { rr[k] = eidx[e];     cc[k] = eidx[E + e]; }
            atomicAdd(&lhist[rr[k] >> BSHIFT], 1);
        }
    }
    __syncthreads();
    for (int i = t; i < NBUK; i += 256) {
        int h = lhist[i];
        lbase[i] = (h > 0) ? atomicAdd(&gcur[i], h) : 0;
        lhist[i] = 0;
    }
    __syncthreads();
    #pragma unroll
    for (int k = 0; k < 8; ++k) {             // scatter from regs (no re-read)
        if (rr[k] >= 0) {
            int b = rr[k] >> BSHIFT;
            int p = atomicAdd(&lhist[b], 1);   // LDS: cheap
            int idx = lbase[b] + p;
            if (idx < BCAP) bucket[b * BCAP + idx] = ((rr[k] & 31) << 24) | cc[k];
        }
    }
}

// ==== Kernel 2: FUSED bucketB (LDS) + pipelined global_load_lds + MFMA ====
// R6 post-mortem: counted vmcnt(4) was defeated because the consumer LDS
// reads were compiler-visible -> hipcc legalized them with s_waitcnt vmcnt(0)
// (the m97 barrier-drain mechanism), serializing every batch to one full
// memory latency (measured 40 cy/edge). FIX: consume the staging buffer via
// inline-asm ds_read_b128 (invisible to the waitcnt legalizer) + explicit
// lgkmcnt(0) + sched_barrier (rule #18). The only vmcnt waits in the loop
// are ours: issue batch k+1, vmcnt(4) = batch k landed, consume batch k.
// WAR on buffer reuse is safe by program order (reads complete into regs
// before batch k+2 is issued). Segments 4-padded (batch=4) -> ~9% dummies.
#define ISSUE(c, bufsel)                                                      \
    {                                                                         \
        ushort_t* db_ = wstage + (bufsel) * 2048;                             \
        __builtin_amdgcn_global_load_lds(                                     \
            (gas_cptr)(xb + (size_t)(c).x * D + 8 * sl),                      \
            (las_ptr)(db_), 16, 0, 0);                                        \
        __builtin_amdgcn_global_load_lds(                                     \
            (gas_cptr)(xb + (size_t)(c).y * D + 8 * sl),                      \
            (las_ptr)(db_ + 512), 16, 0, 0);                                  \
        __builtin_amdgcn_global_load_lds(                                     \
            (gas_cptr)(xb + (size_t)(c).z * D + 8 * sl),                      \
            (las_ptr)(db_ + 1024), 16, 0, 0);                                 \
        __builtin_amdgcn_global_load_lds(                                     \
            (gas_cptr)(xb + (size_t)(c).w * D + 8 * sl),                      \
            (las_ptr)(db_ + 1536), 16, 0, 0);                                 \
    }

#define ACCV(v)                                                               \
    a0 += bf_lo((v)[0]); a1 += bf_hi((v)[0]);                                 \
    a2 += bf_lo((v)[1]); a3 += bf_hi((v)[1]);                                 \
    a4 += bf_lo((v)[2]); a5 += bf_hi((v)[2]);                                 \
    a6 += bf_lo((v)[3]); a7 += bf_hi((v)[3]);

// consume one 4-edge batch from staging buffer `sbp` (asm: invisible to the
// compiler's vmcnt legalizer; data validity is guaranteed by OUR vmcnt wait)
#define CONSUME                                                               \
    {                                                                         \
        uint4_t v0, v1, v2, v3;                                               \
        asm volatile("ds_read_b128 %0, %1"             : "=v"(v0) : "v"(sbp));\
        asm volatile("ds_read_b128 %0, %1 offset:1024" : "=v"(v1) : "v"(sbp));\
        asm volatile("ds_read_b128 %0, %1 offset:2048" : "=v"(v2) : "v"(sbp));\
        asm volatile("ds_read_b128 %0, %1 offset:3072" : "=v"(v3) : "v"(sbp));\
        asm volatile("s_waitcnt lgkmcnt(0)" ::: "memory");                    \
        __builtin_amdgcn_sched_barrier(0);                                    \
        ACCV(v0) ACCV(v1) ACCV(v2) ACCV(v3)                                   \
    }

__global__ __launch_bounds__(256, 3) void fused_bf_kernel(
    const ushort_t* __restrict__ xb, const int* __restrict__ gcur,
    const int* __restrict__ bucket, const ushort_t* __restrict__ Wb,
    const float* __restrict__ bias, float* __restrict__ out, int N) {
    __shared__ alignas(16) int sE[1152];          // 4.5 KiB packed 4-padded list
    __shared__ int lcnt[32], lpos[32], lstart[32];
    __shared__ alignas(16) ushort_t sA[32 * 136]; // 8.5 KiB [n][k] bf16 +pad
    __shared__ alignas(16) ushort_t stage[16384]; // 32 KiB 4 waves x 2 x 4 KB
    int t = threadIdx.x;
    int b = blockIdx.x;

    // ---- step 1: bucketB in LDS ----
    if (t < 32) { lcnt[t] = 0; lpos[t] = 0; }
    __syncthreads();
    int tot = min(gcur[b], BCAP);
    const int* bp = bucket + (size_t)b * BCAP;
    for (int i = t; i < tot; i += 256)
        atomicAdd(&lcnt[bp[i] >> 24], 1);
    __syncthreads();
    if (t == 0) {
        int run = 0;
        #pragma unroll
        for (int i = 0; i < 32; ++i) {
            lstart[i] = run;
            run += (lcnt[i] + 3) & ~3;     // 4-aligned, 4-padded segments
        }                                  // run <= 1024 + 32*3 = 1120 < 1152
    }
    __syncthreads();
    for (int i = t; i < tot; i += 256) {
        int v = bp[i];
        int rl = v >> 24;
        int p = atomicAdd(&lpos[rl], 1);
        int idx = lstart[rl] + p;
        if (idx < 1152) sE[idx] = v & 0xFFFFFF;
    }
    if (t < 32) {                          // pad with dummy (zero) row index N
        int c0 = lcnt[t];
        int pe = (c0 + 3) & ~3;
        for (int p = c0; p < pe; ++p) {
            int idx = lstart[t] + p;
            if (idx < 1152) sE[idx] = N;
        }
    }
    __syncthreads();

    // ---- step 2: gather means -> bf16 LDS A-tile (pipelined staging) ----
    int lane = t & 63, wave = t >> 6;
    int qi = t >> 4, sl = t & 15;          // quarter [0,16), sublane [0,16)
    int nbase = b << BSHIFT;               // 32 rows per block
    ushort_t* wstage = stage + (wave << 12);   // 8 KB (4096 ushorts) per wave

    #pragma unroll
    for (int quad = 0; quad < 2; ++quad) {
        int n = 2 * qi + quad;             // row within bucket [0,32)
        int nr = lcnt[n];
        int st = lstart[n];                // 4-aligned
        int trips = ((nr + 3) & ~3) >> 2;  // 4-edge batches
        int wmax = trips;                  // wave-uniform trip count
        wmax = max(wmax, __shfl_xor(wmax, 16));
        wmax = max(wmax, __shfl_xor(wmax, 32));
        float a0 = 0.f, a1 = 0.f, a2 = 0.f, a3 = 0.f;
        float a4 = 0.f, a5 = 0.f, a6 = 0.f, a7 = 0.f;
        if (wmax > 0) {
            int4 c0 = (0 < trips) ? *(const int4*)(sE + st)
                                  : make_int4(N, N, N, N);
            ISSUE(c0, 0)
            __builtin_amdgcn_sched_barrier(0);
            for (int bt = 0; bt < wmax; ++bt) {
                int buf = bt & 1;
                if (bt + 1 < wmax) {       // wave-uniform branch
                    int4 cn = (bt + 1 < trips)
                        ? *(const int4*)(sE + st + 4 * (bt + 1))
                        : make_int4(N, N, N, N);
                    ISSUE(cn, buf ^ 1)
                    __builtin_amdgcn_sched_barrier(0);
                    asm volatile("s_waitcnt vmcnt(4)" ::: "memory");
                } else {
                    asm volatile("s_waitcnt vmcnt(0)" ::: "memory");
                }
                __builtin_amdgcn_sched_barrier(0);
                las_cushort sbp = (las_cushort)(wstage + buf * 2048 + lane * 8);
                CONSUME
            }
        }
        float inv = (nr > 0) ? 1.0f / (float)nr : 0.0f;
        uint4 pk;
        pk.x = f2bf(a0 * inv) | (f2bf(a1 * inv) << 16);
        pk.y = f2bf(a2 * inv) | (f2bf(a3 * inv) << 16);
        pk.z = f2bf(a4 * inv) | (f2bf(a5 * inv) << 16);
        pk.w = f2bf(a6 * inv) | (f2bf(a7 * inv) << 16);
        *(uint4*)(sA + n * 136 + 8 * sl) = pk;
    }
    __syncthreads();

    // ---- step 3: out[n][j] = mean[n][:] . W[j][:] + b[j]  via MFMA ----
    // 4 waves: rt = wave&1 (2 row-tiles of 16), jgrp = wave>>1 (4 j-tiles).
    // A-frag: lane holds A[l&15][(l>>4)*8 + e];  B = W^T so lane reads
    // W[j = jt*16 + (l&15)][k .. k+7] -- contiguous global bf16.
    {
        int rt = wave & 1, jgrp = wave >> 1;
        int ml = lane & 15, kh = lane >> 4;
        short8_t afr[4];
        #pragma unroll
        for (int ks = 0; ks < 4; ++ks)
            afr[ks] = *(const short8_t*)(sA + (rt * 16 + ml) * 136 + ks * 32 + kh * 8);
        f32x4_t acc[4];
        #pragma unroll
        for (int q = 0; q < 4; ++q) acc[q] = (f32x4_t){0.f, 0.f, 0.f, 0.f};
        #pragma unroll
        for (int q = 0; q < 4; ++q) {
            int j = (jgrp * 4 + q) * 16 + ml;
            #pragma unroll
            for (int ks = 0; ks < 4; ++ks) {
                short8_t bfr = *(const short8_t*)(Wb + (size_t)j * D + ks * 32 + kh * 8);
                acc[q] = __builtin_amdgcn_mfma_f32_16x16x32_bf16(afr[ks], bfr, acc[q], 0, 0, 0);
            }
        }
        // C/D layout: col = lane&15 (j), row = (lane>>4)*4 + reg (n)
        #pragma unroll
        for (int q = 0; q < 4; ++q) {
            int j = (jgrp * 4 + q) * 16 + ml;
            float bj = bias[j];
            #pragma unroll
            for (int r = 0; r < 4; ++r) {
                int gn = nbase + rt * 16 + kh * 4 + r;
                if (gn < N) out[(size_t)gn * D + j] = acc[q][r] + bj;
            }
        }
    }
}

// ---- fallback Pass B: bucket -> packed global elist (fp32 path only) ----
__global__ __launch_bounds__(256) void prep_kernel(
    const int* __restrict__ gcur, const int* __restrict__ bucket,
    int* __restrict__ elist, int* __restrict__ cnt,
    int* __restrict__ start, int N, int NBUK) {
    __shared__ int lcnt[32], lpos[32], lstart[32];
    int t = threadIdx.x;
    int b = blockIdx.x;
    if (t < 32) { lcnt[t] = 0; lpos[t] = 0; }
    __syncthreads();
    int tot = min(gcur[b], BCAP);
    const int* bp = bucket + (size_t)b * BCAP;
    for (int i = t; i < tot; i += 256)
        atomicAdd(&lcnt[bp[i] >> 24], 1);
    __syncthreads();
    if (t == 0) {
        int run = 0;
        #pragma unroll
        for (int i = 0; i < 32; ++i) {
            lstart[i] = run;
            run += (lcnt[i] + 3) & ~3;     // 4-aligned segments
        }
    }
    __syncthreads();
    for (int i = t; i < tot; i += 256) {
        int v = bp[i];
        int rl = v >> 24;
        int p = atomicAdd(&lpos[rl], 1);
        int idx = lstart[rl] + p;
        if (idx < BCAP) elist[(size_t)b * BCAP + idx] = v & 0xFFFFFF;
    }
    if (t < 32) {
        int gr = (b << BSHIFT) + t;
        if (gr < N) { cnt[gr] = lcnt[t]; start[gr] = b * BCAP + lstart[t]; }
    }
}

// ---- fp32 fused variant (proven; used when ws can't hold xb).
// Reads only i < cnt entries. ----
__global__ __launch_bounds__(256, 6) void fused_kernel(
    const float* __restrict__ x, const int* __restrict__ elist,
    const int* __restrict__ cnt, const int* __restrict__ start,
    const float* __restrict__ W, const float* __restrict__ bias,
    float* __restrict__ out, int N) {
    __shared__ float sT[128 * 36];
    __shared__ float wc[16 * 132];
    int t = threadIdx.x;
    int lane = t & 63, wave = t >> 6;
    int half = lane >> 5, sl = lane & 31;
    int nbase = blockIdx.x * 32;

    #pragma unroll
    for (int pair = 0; pair < 4; ++pair) {
        int n = wave * 8 + pair * 2 + half;
        int gn = nbase + n;
        int nr  = (gn < N) ? cnt[gn]   : 0;
        int beg = (gn < N) ? start[gn] : 0;
        int nro  = __shfl(nr, lane ^ 32);
        int both = min(nr, nro);
        float ax = 0.f, ay = 0.f, az = 0.f, aw = 0.f;
        int i = 0;
        for (; i + 8 <= both; i += 8) {
            int4 cA = *(const int4*)(elist + beg + i);
            int4 cB = *(const int4*)(elist + beg + i + 4);
            float4 v0 = *(const float4*)(x + (size_t)cA.x * D + 4 * sl);
            float4 v1 = *(const float4*)(x + (size_t)cA.y * D + 4 * sl);
            float4 v2 = *(const float4*)(x + (size_t)cA.z * D + 4 * sl);
            float4 v3 = *(const float4*)(x + (size_t)cA.w * D + 4 * sl);
            float4 v4 = *(const float4*)(x + (size_t)cB.x * D + 4 * sl);
            float4 v5 = *(const float4*)(x + (size_t)cB.y * D + 4 * sl);
            float4 v6 = *(const float4*)(x + (size_t)cB.z * D + 4 * sl);
            float4 v7 = *(const float4*)(x + (size_t)cB.w * D + 4 * sl);
            ax += ((v0.x + v1.x) + (v2.x + v3.x)) + ((v4.x + v5.x) + (v6.x + v7.x));
            ay += ((v0.y + v1.y) + (v2.y + v3.y)) + ((v4.y + v5.y) + (v6.y + v7.y));
            az += ((v0.z + v1.z) + (v2.z + v3.z)) + ((v4.z + v5.z) + (v6.z + v7.z));
            aw += ((v0.w + v1.w) + (v2.w + v3.w)) + ((v4.w + v5.w) + (v6.w + v7.w));
        }
        for (; i < nr; ++i) {
            int c0 = elist[beg + i];
            float4 v = *(const float4*)(x + (size_t)c0 * D + 4 * sl);
            ax += v.x; ay += v.y; az += v.z; aw += v.w;
        }
        float inv = (nr > 0) ? 1.0f / (float)nr : 0.0f;
        int k0 = 4 * sl;
        sT[(k0 + 0) * 36 + n] = ax * inv;
        sT[(k0 + 1) * 36 + n] = ay * inv;
        sT[(k0 + 2) * 36 + n] = az * inv;
        sT[(k0 + 3) * 36 + n] = aw * inv;
    }

    int jg = t & 31, ng = t >> 5;
    int j0 = jg * 4, n0 = ng * 4;
    float acc[4][4] = {};
    for (int kc = 0; kc < 8; ++kc) {
        __syncthreads();
        #pragma unroll
        for (int i = 0; i < 8; ++i) {
            int idx = t + i * 256;
            int j = idx >> 4, kk = idx & 15;
            wc[kk * 132 + j] = W[j * D + kc * 16 + kk];
        }
        __syncthreads();
        #pragma unroll
        for (int kk = 0; kk < 16; ++kk) {
            int k = kc * 16 + kk;
            float4 s4 = *(const float4*)(sT + k * 36 + n0);
            float4 w4 = *(const float4*)(wc + kk * 132 + j0);
            acc[0][0] = fmaf(s4.x, w4.x, acc[0][0]); acc[0][1] = fmaf(s4.x, w4.y, acc[0][1]);
            acc[0][2] = fmaf(s4.x, w4.z, acc[0][2]); acc[0][3] = fmaf(s4.x, w4.w, acc[0][3]);
            acc[1][0] = fmaf(s4.y, w4.x, acc[1][0]); acc[1][1] = fmaf(s4.y, w4.y, acc[1][1]);
            acc[1][2] = fmaf(s4.y, w4.z, acc[1][2]); acc[1][3] = fmaf(s4.y, w4.w, acc[1][3]);
            acc[2][0] = fmaf(s4.z, w4.x, acc[2][0]); acc[2][1] = fmaf(s4.z, w4.y, acc[2][1]);
            acc[2][2] = fmaf(s4.z, w4.z, acc[2][2]); acc[2][3] = fmaf(s4.z, w4.w, acc[2][3]);
            acc[3][0] = fmaf(s4.w, w4.x, acc[3][0]); acc[3][1] = fmaf(s4.w, w4.y, acc[3][1]);
            acc[3][2] = fmaf(s4.w, w4.z, acc[3][2]); acc[3][3] = fmaf(s4.w, w4.w, acc[3][3]);
        }
    }
    float4 b4 = *(const float4*)(bias + j0);
    #pragma unroll
    for (int i = 0; i < 4; ++i) {
        int gn = nbase + n0 + i;
        if (gn >= N) continue;
        float4 o;
        o.x = acc[i][0] + b4.x;
        o.y = acc[i][1] + b4.y;
        o.z = acc[i][2] + b4.z;
        o.w = acc[i][3] + b4.w;
        *(float4*)(out + (size_t)gn * D + j0) = o;
    }
}

// ==== last-resort fallback: atomic scatter + divide + gemm (proven) ====
__global__ __launch_bounds__(256) void scatter_kernel(
    const float* __restrict__ x, const int* __restrict__ eidx,
    float* summed, float* __restrict__ counts, int E) {
    int t = blockIdx.x * 256 + threadIdx.x;
    int lane = threadIdx.x & 63;
    bool is64 = eidx_is64(eidx);
    int e = t >> 6;
    if (e >= E) return;
    int d = lane * 2;
    int r, c;
    if (is64) { r = eidx[2 * e]; c = eidx[2 * E + 2 * e]; }
    else      { r = eidx[e];     c = eidx[E + e]; }
    float2 v = *(const float2*)(x + (size_t)c * D + d);
    float* dst = summed + (size_t)r * D + d;
    atomicAdd(dst, v.x);
    atomicAdd(dst + 1, v.y);
    if (lane == 0) atomicAdd(counts + r, 1.0f);
}

__global__ __launch_bounds__(256) void divide_kernel(
    float* __restrict__ sums, const float* __restrict__ counts, int N) {
    int g = blockIdx.x * 256 + threadIdx.x;
    int r = g >> 6, lane = g & 63;
    if (r >= N) return;
    float inv = 1.0f / fmaxf(counts[r], 1.0f);
    float2* p = (float2*)(sums + (size_t)r * D + 2 * lane);
    float2 v = *p;
    v.x *= inv; v.y *= inv;
    *p = v;
}

__global__ __launch_bounds__(256) void gemm_kernel(
    float* inout, const float* __restrict__ W,
    const float* __restrict__ bias, int N) {
    __shared__ float sT[128 * 36];
    __shared__ float wc[32 * 132];
    int t = threadIdx.x;
    int nbase = blockIdx.x * 32;
    #pragma unroll
    for (int i = 0; i < 16; ++i) {
        int idx = t + i * 256;
        int n = idx >> 7, k = idx & 127;
        int gn = nbase + n;
        sT[k * 36 + n] = (gn < N) ? inout[(size_t)gn * D + k] : 0.0f;
    }
    int jg = t & 31, ng = t >> 5;
    int j0 = jg * 4, n0 = ng * 4;
    float acc[4][4] = {};
    for (int kc = 0; kc < 4; ++kc) {
        __syncthreads();
        #pragma unroll
        for (int i = 0; i < 16; ++i) {
            int idx = t + i * 256;
            int j = idx >> 5, kk = idx & 31;
            wc[kk * 132 + j] = W[j * D + kc * 32 + kk];
        }
        __syncthreads();
        #pragma unroll 8
        for (int kk = 0; kk < 32; ++kk) {
            int k = kc * 32 + kk;
            float4 s4 = *(const float4*)(sT + k * 36 + n0);
            float4 w4 = *(const float4*)(wc + kk * 132 + j0);
            acc[0][0] = fmaf(s4.x, w4.x, acc[0][0]); acc[0][1] = fmaf(s4.x, w4.y, acc[0][1]);
            acc[0][2] = fmaf(s4.x, w4.z, acc[0][2]); acc[0][3] = fmaf(s4.x, w4.w, acc[0][3]);
            acc[1][0] = fmaf(s4.y, w4.x, acc[1][0]); acc[1][1] = fmaf(s4.y, w4.y, acc[1][1]);
            acc[1][2] = fmaf(s4.y, w4.z, acc[1][2]); acc[1][3] = fmaf(s4.y, w4.w, acc[1][3]);
            acc[2][0] = fmaf(s4.z, w4.x, acc[2][0]); acc[2][1] = fmaf(s4.z, w4.y, acc[2][1]);
            acc[2][2] = fmaf(s4.z, w4.z, acc[2][2]); acc[2][3] = fmaf(s4.z, w4.w, acc[2][3]);
            acc[3][0] = fmaf(s4.w, w4.x, acc[3][0]); acc[3][1] = fmaf(s4.w, w4.y, acc[3][1]);
            acc[3][2] = fmaf(s4.w, w4.z, acc[3][2]); acc[3][3] = fmaf(s4.w, w4.w, acc[3][3]);
        }
    }
    float4 b4 = *(const float4*)(bias + j0);
    #pragma unroll
    for (int i = 0; i < 4; ++i) {
        int gn = nbase + n0 + i;
        if (gn >= N) continue;
        float4 o;
        o.x = acc[i][0] + b4.x;
        o.y = acc[i][1] + b4.y;
        o.z = acc[i][2] + b4.z;
        o.w = acc[i][3] + b4.w;
        *(float4*)(inout + (size_t)gn * D + j0) = o;
    }
}

extern "C" void kernel_launch(void* const* d_in, const int* in_sizes, int n_in,
                              void* d_out, int out_size, void* d_ws, size_t ws_size,
                              hipStream_t stream) {
    // setup_inputs order: x, edge_index, batch_size, num_nodes, W, b
    const float* x = (const float*)d_in[0];
    const int* eidx = (const int*)d_in[1];
    const float* W = (const float*)d_in[4];
    const float* b = (const float*)d_in[5];
    float* out = (float*)d_out;

    int N = in_sizes[0] / D;   // 50000
    int E = in_sizes[1] / 2;   // 800000
    int NBUK = (N + 31) >> BSHIFT;   // 1563
    int ab = (E + EPB_A - 1) / EPB_A;

    // ws layout, 256B-aligned segments (cnt/start/elist used by fallback only).
    size_t o0 = 0;
    size_t o_gc = o0;  o0 += ((size_t)NBUK * 4 + 255) & ~255ULL;
    size_t o_cn = o0;  o0 += ((size_t)N * 4 + 255) & ~255ULL;
    size_t o_st = o0;  o0 += ((size_t)N * 4 + 255) & ~255ULL;
    size_t o_bk = o0;  o0 += (size_t)NBUK * BCAP * 4;
    size_t o_el = o0;  o0 += (size_t)NBUK * BCAP * 4;
    size_t base_need = o0;
    size_t o_xb = o0;  o0 += (((size_t)(N + 1) * D * 2) + 255) & ~255ULL;  // bf16 x + dummy
    size_t o_wb = o0;  size_t bf_need = o0 + (size_t)D * D * 2;            // bf16 W

    bool cap_ok = (N <= 65536) && ((size_t)NBUK * BCAP >= (size_t)E);

    int cvb = (N * D / 8 + 255) / 256;
    int wvb = (D * D / 8 + 255) / 256;   // 8 blocks for W conversion

    if (cap_ok && ws_size >= bf_need) {
        char* ws = (char*)d_ws;
        int*      gcur  = (int*)(ws + o_gc);
        int*      bkt   = (int*)(ws + o_bk);
        ushort_t* xb    = (ushort_t*)(ws + o_xb);
        ushort_t* wb    = (ushort_t*)(ws + o_wb);

        hipMemsetAsync(gcur, 0, (size_t)NBUK * 4, stream);  // 6 KB only
        pre_kernel<<<ab + cvb + wvb, 256, 0, stream>>>(
            eidx, gcur, bkt, E, NBUK, ab,
            x, (uint_t*)xb, N * D / 8, cvb, W, (uint_t*)wb, N);
        fused_bf_kernel<<<NBUK, 256, 0, stream>>>(xb, gcur, bkt, wb, b, out, N);
    } else if (cap_ok && ws_size >= base_need) {
        char* ws = (char*)d_ws;
        int* gcur  = (int*)(ws + o_gc);
        int* cnt   = (int*)(ws + o_cn);
        int* start = (int*)(ws + o_st);
        int* bkt   = (int*)(ws + o_bk);
        int* elist = (int*)(ws + o_el);
        int fb = (N + 31) / 32;

        hipMemsetAsync(gcur, 0, (size_t)NBUK * 4, stream);
        pre_kernel<<<ab, 256, 0, stream>>>(
            eidx, gcur, bkt, E, NBUK, ab,
            nullptr, nullptr, 0, 0, nullptr, nullptr, N);
        prep_kernel<<<NBUK, 256, 0, stream>>>(gcur, bkt, elist, cnt, start, N, NBUK);
        fused_kernel<<<fb, 256, 0, stream>>>(x, elist, cnt, start, W, b, out, N);
    } else {
        float* counts = (float*)d_ws;
        int fb = (N + 31) / 32;
        hipMemsetAsync(d_out, 0, (size_t)N * D * sizeof(float), stream);
        hipMemsetAsync(d_ws, 0, (size_t)N * sizeof(float), stream);
        int sb = (E * 64 + 255) / 256;
        scatter_kernel<<<sb, 256, 0, stream>>>(x, eidx, out, counts, E);
        int db = (N * 64 + 255) / 256;
        divide_kernel<<<db, 256, 0, stream>>>(out, counts, N);
        gemm_kernel<<<fb, 256, 0, stream>>>(out, W, b, N);
    }
}